// Round 1
// 411.016 us; speedup vs baseline: 1.0183x; 1.0183x over previous
//
#include <hip/hip_runtime.h>

// Problem: B=256, N=512, adjacency fp32 [B,N,N], entries BINARY (0/1).
// out[b,i,j] = dinv[b,i] * a_hat[b,i,j] * dinv[b,j]
//   a_hat: diagonal replaced by mask = (rowsum != 0); deg = rowsum - diag + mask
//   dinv  = deg > 0 ? 1/sqrt(deg) : 0
//
// Exactness: a in {0,1} -> di*dj or 0 exactly; diagonal output di*di (mask=0
// => di=0), so folding the diagonal as bit=1 is bit-exact. All degree sums are
// small integers (<=512), exact in fp32 under any summation order.
//
// Round 8: FUSED single kernel, one workgroup per batch (256 blocks, 1/CU).
// Eliminates the global cmp/dinv intermediate AND all workspace usage (the
// harness re-poisons d_ws with 1 GiB fills at ~163us each; decoupling from
// d_ws removes that dependence). Per block: 16 waves x 32 rows stream the
// batch's 1 MB once (NT loads) -> 512-bit row bitmasks in LDS (32 KiB) +
// dinv in LDS (2 KiB) -> one barrier -> same waves expand same rows with NT
// float4 stores. Total HBM traffic = 268 MB in + 268 MB out = streaming floor.

#define NN 512
#define NB 256

typedef float f32x4 __attribute__((ext_vector_type(4)));

__global__ __launch_bounds__(1024) void fused_norm_kernel(
    const float* __restrict__ adj, float* __restrict__ out) {
    __shared__ unsigned char sbits[NN][64];   // 32 KiB: per-row bitmask, diag folded
    __shared__ float sdinv[NN];               // 2 KiB

    const int lane = threadIdx.x & 63;
    const int wave = threadIdx.x >> 6;        // 0..15
    const size_t base = (size_t)blockIdx.x * ((size_t)NN * NN);

    // ---- Phase 1: rowsum -> dinv (LDS), bitmask -> LDS. 32 rows/wave. ----
    #pragma unroll 4
    for (int rr = 0; rr < 32; ++rr) {
        const int i = (wave << 5) + rr;       // row within batch
        const f32x4* r4 = (const f32x4*)(adj + base + (size_t)i * NN);
        f32x4 a0 = __builtin_nontemporal_load(&r4[lane]);       // cols [4l, 4l+4)
        f32x4 a1 = __builtin_nontemporal_load(&r4[lane + 64]);  // cols [256+4l, ..)

        float s = (a0.x + a0.y) + (a0.z + a0.w) + (a1.x + a1.y) + (a1.z + a1.w);

        unsigned nib0 = (a0.x != 0.0f ? 1u : 0u) | (a0.y != 0.0f ? 2u : 0u)
                      | (a0.z != 0.0f ? 4u : 0u) | (a0.w != 0.0f ? 8u : 0u);
        unsigned nib1 = (a1.x != 0.0f ? 1u : 0u) | (a1.y != 0.0f ? 2u : 0u)
                      | (a1.z != 0.0f ? 4u : 0u) | (a1.w != 0.0f ? 8u : 0u);
        unsigned byte = nib0 | (nib1 << 4);

        // diagonal element value (for degree correction)
        float diag = 0.0f;
        const int j0 = lane << 2;
        if (i >= j0 && i < j0 + 4) diag = ((const float*)&a0)[i - j0];
        const int j1 = 256 + j0;
        if (i >= j1 && i < j1 + 4) diag = ((const float*)&a1)[i - j1];

        // fold diagonal bit = 1 into the mask (exact: deg==0 => di==0 => row 0)
        if ((i >> 2) == lane)                       byte |= 1u << (i & 3);
        if (i >= 256 && ((i - 256) >> 2) == lane)   byte |= 1u << (4 + (i & 3));

        sbits[i][lane] = (unsigned char)byte;

        // packed butterfly: T = 2*S + D, all integers <= 1025 (exact in fp32)
        float t = s + s + diag;
        #pragma unroll
        for (int off = 32; off > 0; off >>= 1) t += __shfl_xor(t, off);

        if (lane == 0) {
            float S = floorf(t * 0.5f);       // full rowsum (incl. diagonal)
            float D = t - (S + S);            // diagonal value
            float mask = (S != 0.0f) ? 1.0f : 0.0f;
            float deg  = S - D + mask;
            sdinv[i] = (deg > 0.0f) ? (1.0f / sqrtf(deg)) : 0.0f;
        }
    }

    __syncthreads();

    // ---- Phase 2: out[i][j] = di*dj where bit set. Same wave->row mapping. --
    // dj vectors are loop-invariant per lane: hoist out of the row loop.
    const f32x4 dj0 = ((const f32x4*)sdinv)[lane];        // cols [4l, 4l+4)
    const f32x4 dj1 = ((const f32x4*)sdinv)[lane + 64];   // cols [256+4l, ..)

    #pragma unroll 2
    for (int rr = 0; rr < 32; ++rr) {
        const int i = (wave << 5) + rr;
        const unsigned bb = sbits[i][lane];
        const float di = sdinv[i];                        // LDS broadcast

        f32x4 o0, o1;
        o0.x = (bb &   1u) ? di * dj0.x : 0.0f;
        o0.y = (bb &   2u) ? di * dj0.y : 0.0f;
        o0.z = (bb &   4u) ? di * dj0.z : 0.0f;
        o0.w = (bb &   8u) ? di * dj0.w : 0.0f;
        o1.x = (bb &  16u) ? di * dj1.x : 0.0f;
        o1.y = (bb &  32u) ? di * dj1.y : 0.0f;
        o1.z = (bb &  64u) ? di * dj1.z : 0.0f;
        o1.w = (bb & 128u) ? di * dj1.w : 0.0f;

        f32x4* dst = (f32x4*)(out + base + (size_t)i * NN);
        __builtin_nontemporal_store(o0, &dst[lane]);
        __builtin_nontemporal_store(o1, &dst[lane + 64]);
    }
}

extern "C" void kernel_launch(void* const* d_in, const int* in_sizes, int n_in,
                              void* d_out, int out_size, void* d_ws, size_t ws_size,
                              hipStream_t stream) {
    const float* adj = (const float*)d_in[0];
    float* out = (float*)d_out;
    (void)d_ws; (void)ws_size;  // no workspace: decouple from ws re-poison fills
    fused_norm_kernel<<<NB, 1024, 0, stream>>>(adj, out);
}